// Round 1
// baseline (111.861 us; speedup 1.0000x reference)
//
#include <hip/hip_runtime.h>
#include <math.h>

#define BB 32
#define NN 4096
#define DD 768
#define CC 10
#define KK 16

// ---------------------------------------------------------------------------
// Kernel 1: scores s[b,n] = dot(H[b,n,:], w_score) + b_score
// One 64-lane wave per row, 4 rows per 256-thread block. float4 loads
// (16 B/lane). This kernel reads all 402.7 MB of H -> HBM-bound.
// ---------------------------------------------------------------------------
__global__ __launch_bounds__(256) void score_kernel(
    const float* __restrict__ H, const float* __restrict__ w,
    const float* __restrict__ b_score, float* __restrict__ s) {
  __shared__ __align__(16) float ws[DD];
  for (int i = threadIdx.x; i < DD; i += 256) ws[i] = w[i];
  __syncthreads();

  const int wave = threadIdx.x >> 6;
  const int lane = threadIdx.x & 63;
  const long row = (long)blockIdx.x * 4 + wave;  // in [0, B*N)

  const float4* Hrow = (const float4*)(H + row * DD);
  const float4* wv4 = (const float4*)ws;

  float acc = 0.f;
#pragma unroll
  for (int j = 0; j < 3; ++j) {          // 192 float4 per row / 64 lanes = 3
    const int p = lane + j * 64;
    float4 h = Hrow[p];
    float4 wv = wv4[p];
    acc += h.x * wv.x + h.y * wv.y + h.z * wv.z + h.w * wv.w;
  }
#pragma unroll
  for (int off = 32; off >= 1; off >>= 1) acc += __shfl_xor(acc, off, 64);

  if (lane == 0) s[row] = acc + b_score[0];
}

// ---------------------------------------------------------------------------
// Kernel 2: per-batch top-16 by iterative argmax over LDS-resident scores.
// One block per batch (32 blocks). Tie-break: smaller index (matches lax.top_k).
// ---------------------------------------------------------------------------
__global__ __launch_bounds__(256) void topk_kernel(
    const float* __restrict__ s, int* __restrict__ topk) {
  __shared__ float sv[NN];
  __shared__ float rmax[256];
  __shared__ int ridx[256];

  const int b = blockIdx.x;
  for (int i = threadIdx.x; i < NN; i += 256) sv[i] = s[b * NN + i];
  __syncthreads();

  for (int k = 0; k < KK; ++k) {
    float best = -INFINITY;
    int bi = -1;
    for (int i = threadIdx.x; i < NN; i += 256) {
      float v = sv[i];
      if (v > best) { best = v; bi = i; }   // first hit keeps smallest i
    }
    rmax[threadIdx.x] = best;
    ridx[threadIdx.x] = bi;
    __syncthreads();
#pragma unroll
    for (int stride = 128; stride >= 1; stride >>= 1) {
      if (threadIdx.x < stride) {
        float ov = rmax[threadIdx.x + stride];
        int oi = ridx[threadIdx.x + stride];
        float mv = rmax[threadIdx.x];
        int mi = ridx[threadIdx.x];
        if (ov > mv || (ov == mv && oi >= 0 && (mi < 0 || oi < mi))) {
          rmax[threadIdx.x] = ov;
          ridx[threadIdx.x] = oi;
        }
      }
      __syncthreads();
    }
    if (threadIdx.x == 0) {
      topk[b * KK + k] = ridx[0];
      sv[ridx[0]] = -INFINITY;
    }
    __syncthreads();
  }
}

// ---------------------------------------------------------------------------
// Kernel 3: A[b,n] = (n in topk[b]) ? 1/16 : 0. float4 stores.
// Block = (batch, chunk of 1024 elements); grid = 32*4 = 128 blocks.
// ---------------------------------------------------------------------------
__global__ __launch_bounds__(256) void fillA_kernel(
    const int* __restrict__ topk, float* __restrict__ A) {
  const int b = blockIdx.x >> 2;
  const int chunk = blockIdx.x & 3;
  __shared__ int idx[KK];
  if (threadIdx.x < KK) idx[threadIdx.x] = topk[b * KK + threadIdx.x];
  __syncthreads();

  const int n0 = chunk * 1024 + threadIdx.x * 4;
  float4 v = {0.f, 0.f, 0.f, 0.f};
#pragma unroll
  for (int k = 0; k < KK; ++k) {
    int d = idx[k] - n0;
    if (d == 0) v.x = 0.0625f;
    else if (d == 1) v.y = 0.0625f;
    else if (d == 2) v.z = 0.0625f;
    else if (d == 3) v.w = 0.0625f;
  }
  ((float4*)(A + (long)b * NN))[chunk * 256 + threadIdx.x] = v;
}

// ---------------------------------------------------------------------------
// Kernel 4: M[b,:] = mean of 16 gathered rows; logits[b,:] = M @ W_cls + b_cls.
// One block per batch (32 blocks).
// ---------------------------------------------------------------------------
__global__ __launch_bounds__(256) void logits_kernel(
    const float* __restrict__ H, const int* __restrict__ topk,
    const float* __restrict__ Wc, const float* __restrict__ bc,
    float* __restrict__ out) {
  const int b = blockIdx.x;
  __shared__ float M[DD];
  __shared__ int idx[KK];
  __shared__ float wp[4][CC];

  if (threadIdx.x < KK) idx[threadIdx.x] = topk[b * KK + threadIdx.x];
  __syncthreads();

  for (int d = threadIdx.x; d < DD; d += 256) {
    float acc = 0.f;
#pragma unroll
    for (int k = 0; k < KK; ++k)
      acc += H[((long)b * NN + idx[k]) * DD + d];
    M[d] = acc * (1.f / 16.f);
  }
  __syncthreads();

  float part[CC];
#pragma unroll
  for (int c = 0; c < CC; ++c) part[c] = 0.f;
  for (int d = threadIdx.x; d < DD; d += 256) {
    float m = M[d];
#pragma unroll
    for (int c = 0; c < CC; ++c) part[c] += m * Wc[d * CC + c];
  }
#pragma unroll
  for (int off = 32; off >= 1; off >>= 1) {
#pragma unroll
    for (int c = 0; c < CC; ++c) part[c] += __shfl_xor(part[c], off, 64);
  }
  const int wave = threadIdx.x >> 6;
  const int lane = threadIdx.x & 63;
  if (lane == 0) {
#pragma unroll
    for (int c = 0; c < CC; ++c) wp[wave][c] = part[c];
  }
  __syncthreads();
  if (threadIdx.x < CC) {
    float r = wp[0][threadIdx.x] + wp[1][threadIdx.x] +
              wp[2][threadIdx.x] + wp[3][threadIdx.x];
    out[b * CC + threadIdx.x] = r + bc[threadIdx.x];
  }
}

// ---------------------------------------------------------------------------
extern "C" void kernel_launch(void* const* d_in, const int* in_sizes, int n_in,
                              void* d_out, int out_size, void* d_ws, size_t ws_size,
                              hipStream_t stream) {
  const float* H = (const float*)d_in[0];
  const float* w_score = (const float*)d_in[1];
  const float* b_score = (const float*)d_in[2];
  const float* W_cls = (const float*)d_in[3];
  const float* b_cls = (const float*)d_in[4];

  float* out = (float*)d_out;
  float* logits = out;            // [B, C] = 320 floats
  float* A = out + BB * CC;       // [B, N, 1] = 131072 floats

  float* s = (float*)d_ws;                                    // B*N floats
  int* topk = (int*)((char*)d_ws + (size_t)BB * NN * sizeof(float));  // B*K ints

  score_kernel<<<BB * NN / 4, 256, 0, stream>>>(H, w_score, b_score, s);
  topk_kernel<<<BB, 256, 0, stream>>>(s, topk);
  fillA_kernel<<<BB * 4, 256, 0, stream>>>(topk, A);
  logits_kernel<<<BB, 256, 0, stream>>>(H, topk, W_cls, b_cls, logits);
}

// Round 2
// 101.298 us; speedup vs baseline: 1.1043x; 1.1043x over previous
//
#include <hip/hip_runtime.h>
#include <math.h>

#define BB 32
#define NN 4096
#define DD 768
#define CC 10
#define KK 16

// ---------------------------------------------------------------------------
// Kernel 1: scores s[b,n] = dot(H[b,n,:], w_score) + b_score
// One 64-lane wave per row, 4 rows per 256-thread block. float4 loads
// (16 B/lane). Reads all 402.7 MB of H -> HBM-bound, sets the floor.
// ---------------------------------------------------------------------------
__global__ __launch_bounds__(256) void score_kernel(
    const float* __restrict__ H, const float* __restrict__ w,
    const float* __restrict__ b_score, float* __restrict__ s) {
  __shared__ __align__(16) float ws[DD];
  for (int i = threadIdx.x; i < DD; i += 256) ws[i] = w[i];
  __syncthreads();

  const int wave = threadIdx.x >> 6;
  const int lane = threadIdx.x & 63;
  const long row = (long)blockIdx.x * 4 + wave;  // in [0, B*N)

  const float4* Hrow = (const float4*)(H + row * DD);
  const float4* wv4 = (const float4*)ws;

  float acc = 0.f;
#pragma unroll
  for (int j = 0; j < 3; ++j) {          // 192 float4 per row / 64 lanes = 3
    const int p = lane + j * 64;
    float4 h = Hrow[p];
    float4 wv = wv4[p];
    acc += h.x * wv.x + h.y * wv.y + h.z * wv.z + h.w * wv.w;
  }
#pragma unroll
  for (int off = 32; off >= 1; off >>= 1) acc += __shfl_xor(acc, off, 64);

  if (lane == 0) s[row] = acc + b_score[0];
}

// ---------------------------------------------------------------------------
// Kernel 2 (fused tail): per-batch top-16 (register-resident iterative argmax,
// 2 barriers/iter), A one-hot write, gather+mean, and the 768x10 matvec.
// One block per batch (32 blocks). Tie-break: smaller index (lax.top_k).
// ---------------------------------------------------------------------------
__global__ __launch_bounds__(256) void tail_kernel(
    const float* __restrict__ s, const float* __restrict__ H,
    const float* __restrict__ Wc, const float* __restrict__ bc,
    float* __restrict__ logits, float* __restrict__ A) {
  const int b = blockIdx.x;
  const int t = threadIdx.x;
  const int wave = t >> 6;
  const int lane = t & 63;

  __shared__ float wv[4];
  __shared__ int wi[4];
  __shared__ int winners[KK];
  __shared__ float M[DD];
  __shared__ float wp[4][CC];

  // Each thread owns 16 consecutive scores [t*16, t*16+16) in registers.
  float v[16];
  {
    const float4* sv4 = (const float4*)(s + (long)b * NN);
    float4 a0 = sv4[t * 4 + 0];
    float4 a1 = sv4[t * 4 + 1];
    float4 a2 = sv4[t * 4 + 2];
    float4 a3 = sv4[t * 4 + 3];
    v[0] = a0.x;  v[1] = a0.y;  v[2] = a0.z;  v[3] = a0.w;
    v[4] = a1.x;  v[5] = a1.y;  v[6] = a1.z;  v[7] = a1.w;
    v[8] = a2.x;  v[9] = a2.y;  v[10] = a2.z; v[11] = a2.w;
    v[12] = a3.x; v[13] = a3.y; v[14] = a3.z; v[15] = a3.w;
  }

  // Local running argmax (ascending scan keeps smallest index on ties).
  float lv = v[0];
  int li = t * 16;
#pragma unroll
  for (int j = 1; j < 16; ++j)
    if (v[j] > lv) { lv = v[j]; li = t * 16 + j; }

  for (int k = 0; k < KK; ++k) {
    // Wave-level argmax via butterfly shuffle (no barriers).
    float rv = lv;
    int ri = li;
#pragma unroll
    for (int off = 1; off < 64; off <<= 1) {
      float ov = __shfl_xor(rv, off, 64);
      int oi = __shfl_xor(ri, off, 64);
      if (ov > rv || (ov == rv && oi < ri)) { rv = ov; ri = oi; }
    }
    if (lane == 0) { wv[wave] = rv; wi[wave] = ri; }
    __syncthreads();

    // Cross-wave merge (redundant on all threads, no extra barrier).
    float bv = wv[0];
    int bi = wi[0];
#pragma unroll
    for (int wq = 1; wq < 4; ++wq) {
      float ov = wv[wq];
      int oi = wi[wq];
      if (ov > bv || (ov == bv && oi < bi)) { bv = ov; bi = oi; }
    }
    if (t == 0) winners[k] = bi;

    // Owner thread removes the winner and recomputes its local max.
    if ((bi >> 4) == t) {
      const int slot = bi & 15;
#pragma unroll
      for (int j = 0; j < 16; ++j)
        if (j == slot) v[j] = -INFINITY;
      lv = -INFINITY;
      li = t * 16;
#pragma unroll
      for (int j = 0; j < 16; ++j)
        if (v[j] > lv) { lv = v[j]; li = t * 16 + j; }
    }
    __syncthreads();  // protects wv/wi rewrite; winners[k] visible after loop
  }

  // --- A one-hot write: 4096 floats per batch, float4 stores. ---
#pragma unroll
  for (int jj = 0; jj < 4; ++jj) {
    const int q = t + jj * 256;       // float4 index in [0,1024)
    const int n0 = q * 4;
    float4 av = {0.f, 0.f, 0.f, 0.f};
#pragma unroll
    for (int k = 0; k < KK; ++k) {
      int d = winners[k] - n0;
      if (d == 0) av.x = 0.0625f;
      else if (d == 1) av.y = 0.0625f;
      else if (d == 2) av.z = 0.0625f;
      else if (d == 3) av.w = 0.0625f;
    }
    ((float4*)(A + (long)b * NN))[q] = av;
  }

  // --- Gather 16 rows, mean into M. Coalesced across threads per row. ---
  for (int d = t; d < DD; d += 256) {
    float acc = 0.f;
#pragma unroll
    for (int k = 0; k < KK; ++k)
      acc += H[((long)b * NN + winners[k]) * DD + d];
    M[d] = acc * (1.f / 16.f);
  }
  __syncthreads();

  // --- logits = M @ W_cls + b_cls ---
  float part[CC];
#pragma unroll
  for (int c = 0; c < CC; ++c) part[c] = 0.f;
  for (int d = t; d < DD; d += 256) {
    float m = M[d];
#pragma unroll
    for (int c = 0; c < CC; ++c) part[c] += m * Wc[d * CC + c];
  }
#pragma unroll
  for (int off = 32; off >= 1; off >>= 1) {
#pragma unroll
    for (int c = 0; c < CC; ++c) part[c] += __shfl_xor(part[c], off, 64);
  }
  if (lane == 0) {
#pragma unroll
    for (int c = 0; c < CC; ++c) wp[wave][c] = part[c];
  }
  __syncthreads();
  if (t < CC) {
    float r = wp[0][t] + wp[1][t] + wp[2][t] + wp[3][t];
    logits[b * CC + t] = r + bc[t];
  }
}

// ---------------------------------------------------------------------------
extern "C" void kernel_launch(void* const* d_in, const int* in_sizes, int n_in,
                              void* d_out, int out_size, void* d_ws, size_t ws_size,
                              hipStream_t stream) {
  const float* H = (const float*)d_in[0];
  const float* w_score = (const float*)d_in[1];
  const float* b_score = (const float*)d_in[2];
  const float* W_cls = (const float*)d_in[3];
  const float* b_cls = (const float*)d_in[4];

  float* out = (float*)d_out;
  float* logits = out;            // [B, C] = 320 floats
  float* A = out + BB * CC;       // [B, N, 1] = 131072 floats

  float* s = (float*)d_ws;        // B*N floats of scratch

  score_kernel<<<BB * NN / 4, 256, 0, stream>>>(H, w_score, b_score, s);
  tail_kernel<<<BB, 256, 0, stream>>>(s, H, W_cls, b_cls, logits, A);
}